// Round 7
// baseline (438.666 us; speedup 1.0000x reference)
//
#include <hip/hip_runtime.h>

#define N_ROWS 65536
#define NE 1024
#define ED 64
#define ERR_GAP 8e-5f

static const size_t OFF_ZQ = 1;
static const size_t OFF_ME = 1 + 4194304;
static const size_t OFF_IDX = OFF_ME + (size_t)N_ROWS * NE;
#define ME_FLOATS ((size_t)N_ROWS * NE)   // 67108864
#define NBLK_ZQ 16384

// scratch layout in the one-hot region from base = me+3 (16B aligned); all
// consumed before k_fill zeroes it.
#define SC_CM      0              // [8*65536] per-chunk min
#define SC_CS      524288         // [8*65536] per-chunk 2nd-min
#define SC_CI      1048576        // [8*65536] per-chunk argmin (int bits)
#define SC_Z2      1572864        // [65536]
#define SC_PARTIAL 1638400        // [16384]
#define SC_FLAG    1654784        // [65536] int

typedef __attribute__((ext_vector_type(8))) short short8v;  // 8 bf16 (guide §3)
typedef __attribute__((ext_vector_type(4))) float f32x4;

__device__ __forceinline__ unsigned bf16_rne(float v) {
  unsigned u = __float_as_uint(v);
  return (u + 0x7FFFu + ((u >> 16) & 1u)) >> 16;
}

// ---- e2[j] = numpy pairwise sum of cb[j]^2 (bit-exact); also cnt=0 ----
__global__ void k_e2(const float* __restrict__ cb, float* __restrict__ e2,
                     int* __restrict__ cnt) {
  const int j = blockIdx.x * 64 + threadIdx.x;
  if (j == 0) *cnt = 0;
  if (j >= NE) return;
  const float* __restrict__ e = cb + (size_t)j * ED;
  float r[8];
  #pragma unroll
  for (int i = 0; i < 8; ++i) {
    float v = e[i]; float q = v * v;
    asm volatile("" : "+v"(q)); r[i] = q;
  }
  #pragma unroll
  for (int k = 1; k < 8; ++k)
    #pragma unroll
    for (int i = 0; i < 8; ++i) {
      float v = e[8 * k + i]; float q = v * v;
      asm volatile("" : "+v"(q)); r[i] += q;
    }
  e2[j] = ((r[0] + r[1]) + (r[2] + r[3])) + ((r[4] + r[5]) + (r[6] + r[7]));
}

// ---- z2[n] = numpy pairwise sum of z-row squares (bit-exact) ----
__global__ void k_z2(const float* __restrict__ z, float* __restrict__ z2) {
  const int n = blockIdx.x * 256 + threadIdx.x;
  const int b = n >> 10, hw = n & 1023;
  const float* __restrict__ zp = z + (size_t)b * 65536 + hw;
  float r[8];
  #pragma unroll
  for (int i = 0; i < 8; ++i) {
    const float v = zp[(size_t)i << 10];
    float q = v * v; asm volatile("" : "+v"(q)); r[i] = q;
  }
  #pragma unroll
  for (int k = 1; k < 8; ++k)
    #pragma unroll
    for (int i = 0; i < 8; ++i) {
      const float v = zp[(size_t)(8 * k + i) << 10];
      float q = v * v; asm volatile("" : "+v"(q)); r[i] += q;
    }
  z2[n] = ((r[0] + r[1]) + (r[2] + r[3])) + ((r[4] + r[5]) + (r[6] + r[7]));
}

// ---- split-bf16 MFMA distance prefilter ----
// Block: 256 thr = 4 waves; tile 64 rows x 128 cols (chunk), K=192
// (A=[zh,zh,zl], B=[eh,el,eh]). Per wave: cols w*32..+31, all 64 rows,
// 8 tiles of 16x16, 6 K-steps of mfma_f32_16x16x32_bf16. Epilogue tracks
// per-row (min, 2nd-min, argmin) with lexicographic (v, idx) merges.
__global__ __launch_bounds__(256, 2) void k_mfma(const float* __restrict__ z,
    const float* __restrict__ cb, const float* __restrict__ e2,
    const float* __restrict__ z2g, float* __restrict__ cm,
    float* __restrict__ cs, int* __restrict__ ci) {
  __shared__ short A[64][200];    // [row][K=192 +8 pad]
  __shared__ short B[128][200];   // [col][K]
  __shared__ float sm[4][64], ss[4][64];
  __shared__ int   si[4][64];
  const int t = threadIdx.x;
  const int row0 = blockIdx.x * 64;
  const int chunk = blockIdx.y;
  const int b = row0 >> 10, hw0 = row0 & 1023;

  // stage A: zh at k, zh at 64+k, zl at 128+k
  {
    const int r = t & 63, dg = t >> 6;
    const float* __restrict__ zp = z + (size_t)b * 65536 + hw0 + r;
    #pragma unroll
    for (int rep = 0; rep < 4; ++rep) {
      const int d0 = dg * 16 + rep * 4;
      short h[4], l[4];
      #pragma unroll
      for (int i = 0; i < 4; ++i) {
        const float v = zp[(size_t)(d0 + i) << 10];
        const unsigned hb = bf16_rne(v);
        const float res = v - __uint_as_float(hb << 16);
        h[i] = (short)hb; l[i] = (short)bf16_rne(res);
      }
      *(short4*)&A[r][d0]       = make_short4(h[0], h[1], h[2], h[3]);
      *(short4*)&A[r][64 + d0]  = make_short4(h[0], h[1], h[2], h[3]);
      *(short4*)&A[r][128 + d0] = make_short4(l[0], l[1], l[2], l[3]);
    }
  }
  // stage B: eh at k, el at 64+k, eh at 128+k
  {
    const int c = t >> 1, kh = (t & 1) * 32;
    const float* __restrict__ ep = cb + (size_t)(chunk * 128 + c) * ED + kh;
    #pragma unroll
    for (int rep = 0; rep < 8; ++rep) {
      const float4 v4 = *(const float4*)(ep + rep * 4);
      const float vv[4] = {v4.x, v4.y, v4.z, v4.w};
      short h[4], l[4];
      #pragma unroll
      for (int i = 0; i < 4; ++i) {
        const unsigned hb = bf16_rne(vv[i]);
        const float res = vv[i] - __uint_as_float(hb << 16);
        h[i] = (short)hb; l[i] = (short)bf16_rne(res);
      }
      const int k0 = kh + rep * 4;
      *(short4*)&B[c][k0]       = make_short4(h[0], h[1], h[2], h[3]);
      *(short4*)&B[c][64 + k0]  = make_short4(l[0], l[1], l[2], l[3]);
      *(short4*)&B[c][128 + k0] = make_short4(h[0], h[1], h[2], h[3]);
    }
  }
  __syncthreads();

  const int w = t >> 6, lane = t & 63;
  const int c0 = w * 32;
  const int arow = lane & 15;
  const int kgrp = (lane >> 4) * 8;

  f32x4 acc[4][2];
  #pragma unroll
  for (int rt = 0; rt < 4; ++rt)
    #pragma unroll
    for (int ct = 0; ct < 2; ++ct) acc[rt][ct] = (f32x4)(0.0f);

  #pragma unroll
  for (int ks = 0; ks < 6; ++ks) {
    const int kk = ks * 32 + kgrp;
    short8v bf[2];
    #pragma unroll
    for (int ct = 0; ct < 2; ++ct)
      bf[ct] = *(const short8v*)&B[c0 + ct * 16 + arow][kk];
    #pragma unroll
    for (int rt = 0; rt < 4; ++rt) {
      const short8v af = *(const short8v*)&A[rt * 16 + arow][kk];
      #pragma unroll
      for (int ct = 0; ct < 2; ++ct)
        acc[rt][ct] = __builtin_amdgcn_mfma_f32_16x16x32_bf16(af, bf[ct], acc[rt][ct], 0, 0, 0);
    }
  }

  // epilogue: d = fl(fl(z2+e2) - 2*dot_approx); per-row triple reduce
  const int jbase = chunk * 128 + c0 + (lane & 15);
  #pragma unroll
  for (int rt = 0; rt < 4; ++rt) {
    #pragma unroll
    for (int reg = 0; reg < 4; ++reg) {
      const int rloc = rt * 16 + (lane >> 4) * 4 + reg;
      const float z2v = z2g[row0 + rloc];
      const float v0 = (z2v + e2[jbase]) - 2.0f * acc[rt][0][reg];
      const float v1 = (z2v + e2[jbase + 16]) - 2.0f * acc[rt][1][reg];
      float m, s; int bi;
      if (v1 < v0) { m = v1; s = v0; bi = jbase + 16; }
      else         { m = v0; s = v1; bi = jbase; }
      #pragma unroll
      for (int off = 1; off < 16; off <<= 1) {
        const float om = __shfl_xor(m, off, 64);
        const float os = __shfl_xor(s, off, 64);
        const int   oi = __shfl_xor(bi, off, 64);
        if (om < m || (om == m && oi < bi)) { s = fminf(m, os); m = om; bi = oi; }
        else { s = fminf(s, om); }
      }
      if ((lane & 15) == 0) { sm[w][rloc] = m; ss[w][rloc] = s; si[w][rloc] = bi; }
    }
  }
  __syncthreads();
  if (t < 64) {
    float m = sm[0][t], s = ss[0][t]; int bi = si[0][t];
    #pragma unroll
    for (int ww = 1; ww < 4; ++ww) {
      const float om = sm[ww][t], os = ss[ww][t]; const int oi = si[ww][t];
      if (om < m || (om == m && oi < bi)) { s = fminf(m, os); m = om; bi = oi; }
      else { s = fminf(s, om); }
    }
    cm[(size_t)chunk * N_ROWS + row0 + t] = m;
    cs[(size_t)chunk * N_ROWS + row0 + t] = s;
    ci[(size_t)chunk * N_ROWS + row0 + t] = bi;
  }
}

// ---- merge 8 chunks; flag rows whose approx gap < ERR_GAP ----
__global__ void k_mergec(const float* __restrict__ cm, const float* __restrict__ cs,
                         const int* __restrict__ ci, float* __restrict__ idxf,
                         int* __restrict__ flagged, int* __restrict__ cnt) {
  const int n = blockIdx.x * 256 + threadIdx.x;
  float m = cm[n], s = cs[n]; int bi = ci[n];
  #pragma unroll
  for (int c = 1; c < 8; ++c) {
    const float om = cm[(size_t)c * N_ROWS + n];
    const float os = cs[(size_t)c * N_ROWS + n];
    const int   oi = ci[(size_t)c * N_ROWS + n];
    if (om < m || (om == m && oi < bi)) { s = fminf(m, os); m = om; bi = oi; }
    else { s = fminf(s, om); }
  }
  idxf[n] = (float)bi;
  if (s - m < ERR_GAP) {
    const int slot = atomicAdd(cnt, 1);
    flagged[slot] = n;
  }
}

// ---- exact rescan of flagged rows (round-2-verified arithmetic) ----
__global__ void k_exact(const float* __restrict__ z, const float* __restrict__ cb,
                        const float* __restrict__ e2, const float* __restrict__ z2g,
                        const int* __restrict__ flagged, const int* __restrict__ cnt,
                        float* __restrict__ idxf) {
  __shared__ float Z[4][64];
  const int wv = threadIdx.x >> 6, lane = threadIdx.x & 63;
  const int gw = blockIdx.x * 4 + wv, nw = gridDim.x * 4;
  const int count = *cnt;
  for (int i = gw; i < count; i += nw) {
    const int n = flagged[i];
    const int b = n >> 10, hw = n & 1023;
    Z[wv][lane] = z[(size_t)b * 65536 + ((size_t)lane << 10) + hw];
    __builtin_amdgcn_wave_barrier();
    const float z2v = z2g[n];
    float bm = 1e30f; int bi = 0;
    for (int q = 0; q < 16; ++q) {
      const int j = lane * 16 + q;
      const float* __restrict__ e = cb + (size_t)j * ED;
      float a = 0.0f;
      #pragma unroll
      for (int k = 0; k < ED; ++k) a = fmaf(Z[wv][k], e[k], a);  // sequential f32 chain
      const float d = (z2v + e2[j]) - 2.0f * a;
      if (d < bm) { bm = d; bi = j; }   // ascending j within lane, strict <
    }
    #pragma unroll
    for (int off = 1; off < 64; off <<= 1) {
      const float om = __shfl_xor(bm, off, 64);
      const int   oi = __shfl_xor(bi, off, 64);
      if (om < bm || (om == bm && oi < bi)) { bm = om; bi = oi; }
    }
    if (lane == 0) idxf[n] = (float)bi;
    __builtin_amdgcn_wave_barrier();
  }
}

// ---- z_q gather + per-block loss partial ----
__global__ __launch_bounds__(256) void k_zq(const float* __restrict__ z,
    const float* __restrict__ cb, const float* __restrict__ idxf,
    float* __restrict__ zq, float* __restrict__ partial) {
  const int o = blockIdx.x * 256 + threadIdx.x;
  const int b = o >> 16;
  const int d = (o >> 10) & 63;
  const int hw = o & 1023;
  const int n = (b << 10) + hw;
  const int idx = (int)idxf[n];
  const float v = cb[(size_t)idx * ED + d];
  zq[o] = v;
  const float diff = z[o] - v;
  float s = diff * diff;
  #pragma unroll
  for (int off = 32; off > 0; off >>= 1) s += __shfl_xor(s, off, 64);
  __shared__ float sh[4];
  if ((threadIdx.x & 63) == 0) sh[threadIdx.x >> 6] = s;
  __syncthreads();
  if (threadIdx.x == 0)
    partial[blockIdx.x] = (sh[0] + sh[1]) + (sh[2] + sh[3]);
}

__global__ void k_loss(const float* __restrict__ partial, float* __restrict__ out0) {
  const int t = threadIdx.x;
  double s = 0.0;
  #pragma unroll
  for (int k = 0; k < NBLK_ZQ / 256; ++k) s += (double)partial[t + (k << 8)];
  #pragma unroll
  for (int off = 32; off > 0; off >>= 1) s += __shfl_xor(s, off, 64);
  __shared__ double sh[4];
  if ((t & 63) == 0) sh[t >> 6] = s;
  __syncthreads();
  if (t == 0)
    out0[0] = (float)(1.25 * ((sh[0] + sh[1]) + (sh[2] + sh[3])) / 4194304.0);
}

__global__ __launch_bounds__(256) void k_fill(float* __restrict__ me) {
  const size_t n4 = (ME_FLOATS - 3) >> 2;
  float4* __restrict__ p4 = reinterpret_cast<float4*>(me + 3);
  const size_t stride = (size_t)gridDim.x * blockDim.x;
  const float4 zero4 = make_float4(0.f, 0.f, 0.f, 0.f);
  for (size_t i = blockIdx.x * (size_t)blockDim.x + threadIdx.x; i < n4; i += stride)
    p4[i] = zero4;
  if (blockIdx.x == 0 && threadIdx.x == 0) {
    me[0] = 0.f; me[1] = 0.f; me[2] = 0.f;
    me[ME_FLOATS - 1] = 0.f;
  }
}

__global__ void k_scatter(const float* __restrict__ idxf, float* __restrict__ me) {
  const int n = blockIdx.x * 256 + threadIdx.x;
  const int idx = (int)idxf[n];
  me[(size_t)n * NE + idx] = 1.0f;
}

extern "C" void kernel_launch(void* const* d_in, const int* in_sizes, int n_in,
                              void* d_out, int out_size, void* d_ws, size_t ws_size,
                              hipStream_t stream) {
  const float* z  = (const float*)d_in[0];
  const float* cb = (const float*)d_in[1];
  float* out  = (float*)d_out;
  float* zq   = out + OFF_ZQ;
  float* me   = out + OFF_ME;
  float* idxf = out + OFF_IDX;
  float* base = me + 3;
  float* cm      = base + SC_CM;
  float* cs      = base + SC_CS;
  int*   ci      = (int*)(base + SC_CI);
  float* z2      = base + SC_Z2;
  float* partial = base + SC_PARTIAL;
  int*   flagged = (int*)(base + SC_FLAG);
  float* e2  = (float*)((char*)d_ws + 16);
  int*   cnt = (int*)((char*)d_ws + 8);

  k_e2<<<16, 64, 0, stream>>>(cb, e2, cnt);
  k_z2<<<N_ROWS / 256, 256, 0, stream>>>(z, z2);
  k_mfma<<<dim3(N_ROWS / 64, 8), 256, 0, stream>>>(z, cb, e2, z2, cm, cs, ci);
  k_mergec<<<N_ROWS / 256, 256, 0, stream>>>(cm, cs, ci, idxf, flagged, cnt);
  k_exact<<<128, 256, 0, stream>>>(z, cb, e2, z2, flagged, cnt, idxf);
  k_zq<<<NBLK_ZQ, 256, 0, stream>>>(z, cb, idxf, zq, partial);
  k_loss<<<1, 256, 0, stream>>>(partial, out);
  k_fill<<<2048, 256, 0, stream>>>(me);
  k_scatter<<<N_ROWS / 256, 256, 0, stream>>>(idxf, me);
}

// Round 8
// 222.092 us; speedup vs baseline: 1.9752x; 1.9752x over previous
//
#include <hip/hip_runtime.h>

#define N_ROWS 65536
#define NE 1024
#define ED 64
#define ERR_GAP 8e-5f

static const size_t OFF_ZQ = 1;
static const size_t OFF_ME = 1 + 4194304;
static const size_t OFF_IDX = OFF_ME + (size_t)N_ROWS * NE;
#define ME_FLOATS ((size_t)N_ROWS * NE)   // 67108864
#define NBLK_ZQ 16384

// scratch (float offsets) from base = me+3 (16B aligned); all consumed before k_fill.
#define SC_ZFRAG   0           // 4194304 floats = 16MB (8.4M bf16 shorts)
#define SC_CBFRAG  4194304     // 65536 floats = 256KB
#define SC_Z2      4259840     // 65536
#define SC_PARTIAL 4325376     // 16384
#define SC_FLAG    4341760     // 65536 ints

typedef __attribute__((ext_vector_type(8))) short short8v;  // 8 bf16 = 4 VGPR
typedef __attribute__((ext_vector_type(4))) float f32x4;

__device__ __forceinline__ unsigned bf16_rne(float v) {
  unsigned u = __float_as_uint(v);
  return (u + 0x7FFFu + ((u >> 16) & 1u)) >> 16;
}

// async global->LDS, 16B per lane, LDS dest = wave-uniform base + lane*16
__device__ __forceinline__ void gld16(const void* g, void* l) {
  __builtin_amdgcn_global_load_lds(
      (const __attribute__((address_space(1))) void*)g,
      (__attribute__((address_space(3))) void*)l, 16, 0, 0);
}

// ---- split z into bf16 hi/lo, packed in MFMA A-fragment order ----
// zfrag[rt][hl][ks][lane][8]: rt=n>>4 (4096), row=lane&15, k=ks*32+(lane>>4)*8+i
__global__ __launch_bounds__(256) void k_split_z(const float* __restrict__ z,
                                                 short* __restrict__ zfrag) {
  const int tid = blockIdx.x * 256 + threadIdx.x;
  const int rt = tid >> 6, lane = tid & 63;
  const int n = rt * 16 + (lane & 15);
  const int b = n >> 10, hw = n & 1023;
  const float* __restrict__ zp = z + (size_t)b * 65536 + hw;
  const int k0 = (lane >> 4) * 8;
  short* __restrict__ o = zfrag + (size_t)rt * 2048 + lane * 8;
  #pragma unroll
  for (int ks = 0; ks < 2; ++ks) {
    short h[8], lo[8];
    #pragma unroll
    for (int i = 0; i < 8; ++i) {
      const float v = zp[(size_t)(ks * 32 + k0 + i) << 10];
      const unsigned hb = bf16_rne(v);
      const float res = v - __uint_as_float(hb << 16);
      h[i] = (short)hb; lo[i] = (short)bf16_rne(res);
    }
    *(short8v*)(o + (size_t)(0 * 2 + ks) * 512) = *(short8v*)h;
    *(short8v*)(o + (size_t)(1 * 2 + ks) * 512) = *(short8v*)lo;
  }
}

// ---- split codebook into bf16 hi/lo, packed in MFMA B-fragment order ----
// cbfrag[ct][hl][ks][lane][8]: ct (64), col=ct*16+(lane&15), k=ks*32+(lane>>4)*8+i
__global__ __launch_bounds__(256) void k_split_cb(const float* __restrict__ cb,
                                                  short* __restrict__ cbfrag) {
  const int tid = blockIdx.x * 256 + threadIdx.x;
  const int ct = tid >> 6, lane = tid & 63;
  const int col = ct * 16 + (lane & 15);
  const int k0 = (lane >> 4) * 8;
  const float* __restrict__ ep = cb + (size_t)col * ED + k0;
  short* __restrict__ o = cbfrag + (size_t)ct * 2048 + lane * 8;
  #pragma unroll
  for (int ks = 0; ks < 2; ++ks) {
    short h[8], lo[8];
    #pragma unroll
    for (int i = 0; i < 8; ++i) {
      const float v = ep[ks * 32 + i];
      const unsigned hb = bf16_rne(v);
      const float res = v - __uint_as_float(hb << 16);
      h[i] = (short)hb; lo[i] = (short)bf16_rne(res);
    }
    *(short8v*)(o + (size_t)(0 * 2 + ks) * 512) = *(short8v*)h;
    *(short8v*)(o + (size_t)(1 * 2 + ks) * 512) = *(short8v*)lo;
  }
}

// ---- e2[j] = numpy pairwise sum of cb[j]^2 (bit-exact); also cnt=0 ----
__global__ void k_e2(const float* __restrict__ cb, float* __restrict__ e2,
                     int* __restrict__ cnt) {
  const int j = blockIdx.x * 64 + threadIdx.x;
  if (j == 0) *cnt = 0;
  if (j >= NE) return;
  const float* __restrict__ e = cb + (size_t)j * ED;
  float r[8];
  #pragma unroll
  for (int i = 0; i < 8; ++i) {
    float v = e[i]; float q = v * v;
    asm volatile("" : "+v"(q)); r[i] = q;
  }
  #pragma unroll
  for (int k = 1; k < 8; ++k)
    #pragma unroll
    for (int i = 0; i < 8; ++i) {
      float v = e[8 * k + i]; float q = v * v;
      asm volatile("" : "+v"(q)); r[i] += q;
    }
  e2[j] = ((r[0] + r[1]) + (r[2] + r[3])) + ((r[4] + r[5]) + (r[6] + r[7]));
}

// ---- z2[n] = numpy pairwise sum of z-row squares (bit-exact) ----
__global__ void k_z2(const float* __restrict__ z, float* __restrict__ z2) {
  const int n = blockIdx.x * 256 + threadIdx.x;
  const int b = n >> 10, hw = n & 1023;
  const float* __restrict__ zp = z + (size_t)b * 65536 + hw;
  float r[8];
  #pragma unroll
  for (int i = 0; i < 8; ++i) {
    const float v = zp[(size_t)i << 10];
    float q = v * v; asm volatile("" : "+v"(q)); r[i] = q;
  }
  #pragma unroll
  for (int k = 1; k < 8; ++k)
    #pragma unroll
    for (int i = 0; i < 8; ++i) {
      const float v = zp[(size_t)(8 * k + i) << 10];
      float q = v * v; asm volatile("" : "+v"(q)); r[i] += q;
    }
  z2[n] = ((r[0] + r[1]) + (r[2] + r[3])) + ((r[4] + r[5]) + (r[6] + r[7]));
}

// ---- MFMA distance + fused (min,2nd,argmin) + flagging ----
// Block 256 thr = 4 waves, 128 rows, all 1024 cols (8 chunks of 128 looped).
// Wave w owns rows w*32..w*32+31 (local row-tiles w*2, w*2+1). A-frags held in
// registers across chunks; B staged per chunk via global_load_lds (linear,
// conflict-free). 3 split-products (zh*eh, zh*el, zl*eh) x 2 K-steps chained
// into one acc per 16x16 tile (order identical to round 7 => same flag set).
__global__ __launch_bounds__(256, 2) void k_mfma2(
    const short* __restrict__ zfrag, const short* __restrict__ cbfrag,
    const float* __restrict__ e2g, const float* __restrict__ z2g,
    float* __restrict__ idxf, int* __restrict__ flagged, int* __restrict__ cnt) {
  __shared__ short lA[16384];   // 32KB: 8 rt x [hl][ks][lane][8]
  __shared__ short lB[16384];   // 32KB: 8 ct x [hl][ks][lane][8]
  const int t = threadIdx.x, w = t >> 6, lane = t & 63;
  const int row0 = blockIdx.x * 128;
  const short* gA = zfrag + (size_t)blockIdx.x * 16384;

  #pragma unroll
  for (int i = 0; i < 8; ++i) {
    const int off = (i * 4 + w) * 512;
    gld16(gA + off + lane * 8, lA + off);
    gld16(cbfrag + off + lane * 8, lB + off);
  }
  __syncthreads();

  short8v a[2][2][2];   // [rt][hl][ks], reused across all chunks
  #pragma unroll
  for (int rt = 0; rt < 2; ++rt)
    #pragma unroll
    for (int hl = 0; hl < 2; ++hl)
      #pragma unroll
      for (int ks = 0; ks < 2; ++ks)
        a[rt][hl][ks] = *(const short8v*)&lA[((w * 2 + rt) * 4 + hl * 2 + ks) * 512 + lane * 8];

  float z2r[2][4];
  #pragma unroll
  for (int rt = 0; rt < 2; ++rt)
    #pragma unroll
    for (int reg = 0; reg < 4; ++reg)
      z2r[rt][reg] = z2g[row0 + w * 32 + rt * 16 + (lane >> 4) * 4 + reg];

  float Tm[2][4], Ts[2][4]; int Tb[2][4];
  #pragma unroll
  for (int rt = 0; rt < 2; ++rt)
    #pragma unroll
    for (int reg = 0; reg < 4; ++reg) { Tm[rt][reg] = 1e30f; Ts[rt][reg] = 1e30f; Tb[rt][reg] = 0; }

  for (int c = 0; c < 8; ++c) {
    #pragma unroll
    for (int ctp = 0; ctp < 4; ++ctp) {
      short8v bfr[2][2][2];   // [cc][hl][ks]
      #pragma unroll
      for (int cc = 0; cc < 2; ++cc)
        #pragma unroll
        for (int hl = 0; hl < 2; ++hl)
          #pragma unroll
          for (int ks = 0; ks < 2; ++ks)
            bfr[cc][hl][ks] = *(const short8v*)&lB[((ctp * 2 + cc) * 4 + hl * 2 + ks) * 512 + lane * 8];

      f32x4 acc[2][2];
      #pragma unroll
      for (int rt = 0; rt < 2; ++rt)
        #pragma unroll
        for (int cc = 0; cc < 2; ++cc) acc[rt][cc] = (f32x4)(0.0f);

      // pairs (a_hl, b_hl): (h,h) (h,l) (l,h), ks-inner: same order as round 7
      #pragma unroll
      for (int p = 0; p < 3; ++p) {
        const int pa = (p == 2) ? 1 : 0;
        const int pb = (p == 1) ? 1 : 0;
        #pragma unroll
        for (int ks = 0; ks < 2; ++ks)
          #pragma unroll
          for (int rt = 0; rt < 2; ++rt)
            #pragma unroll
            for (int cc = 0; cc < 2; ++cc)
              acc[rt][cc] = __builtin_amdgcn_mfma_f32_16x16x32_bf16(
                  a[rt][pa][ks], bfr[cc][pb][ks], acc[rt][cc], 0, 0, 0);
      }

      // epilogue: d = fl(fl(z2+e2) - 2*dot); in-lane (m,s,bi), j ascending
      #pragma unroll
      for (int cc = 0; cc < 2; ++cc) {
        const int j = c * 128 + (ctp * 2 + cc) * 16 + (lane & 15);
        const float e2v = e2g[j];
        #pragma unroll
        for (int rt = 0; rt < 2; ++rt)
          #pragma unroll
          for (int reg = 0; reg < 4; ++reg) {
            const float dd = (z2r[rt][reg] + e2v) - 2.0f * acc[rt][cc][reg];
            if (dd < Tm[rt][reg]) {
              Ts[rt][reg] = Tm[rt][reg]; Tm[rt][reg] = dd; Tb[rt][reg] = j;
            } else {
              Ts[rt][reg] = fminf(Ts[rt][reg], dd);
            }
          }
      }
    }
    __syncthreads();
    if (c < 7) {
      const short* gB = cbfrag + (size_t)(c + 1) * 16384;
      #pragma unroll
      for (int i = 0; i < 8; ++i) {
        const int off = (i * 4 + w) * 512;
        gld16(gB + off + lane * 8, lB + off);
      }
      __syncthreads();
    }
  }

  // 16-lane butterfly (cols of each tile) then write idxf + flag
  #pragma unroll
  for (int rt = 0; rt < 2; ++rt)
    #pragma unroll
    for (int reg = 0; reg < 4; ++reg) {
      float m = Tm[rt][reg], s = Ts[rt][reg]; int bi = Tb[rt][reg];
      #pragma unroll
      for (int off = 1; off < 16; off <<= 1) {
        const float om = __shfl_xor(m, off, 64);
        const float os = __shfl_xor(s, off, 64);
        const int   oi = __shfl_xor(bi, off, 64);
        if (om < m || (om == m && oi < bi)) { s = fminf(m, os); m = om; bi = oi; }
        else { s = fminf(s, om); }
      }
      if ((lane & 15) == 0) {
        const int n = row0 + w * 32 + rt * 16 + (lane >> 4) * 4 + reg;
        idxf[n] = (float)bi;
        if (s - m < ERR_GAP) {
          const int slot = atomicAdd(cnt, 1);
          flagged[slot] = n;
        }
      }
    }
}

// ---- exact rescan of flagged rows (round-2-verified arithmetic) ----
__global__ void k_exact(const float* __restrict__ z, const float* __restrict__ cb,
                        const float* __restrict__ e2, const float* __restrict__ z2g,
                        const int* __restrict__ flagged, const int* __restrict__ cnt,
                        float* __restrict__ idxf) {
  __shared__ float Z[4][64];
  const int wv = threadIdx.x >> 6, lane = threadIdx.x & 63;
  const int gw = blockIdx.x * 4 + wv, nw = gridDim.x * 4;
  const int count = *cnt;
  for (int i = gw; i < count; i += nw) {
    const int n = flagged[i];
    const int b = n >> 10, hw = n & 1023;
    Z[wv][lane] = z[(size_t)b * 65536 + ((size_t)lane << 10) + hw];
    __builtin_amdgcn_wave_barrier();
    const float z2v = z2g[n];
    float bm = 1e30f; int bi = 0;
    for (int q = 0; q < 16; ++q) {
      const int j = lane * 16 + q;
      const float* __restrict__ e = cb + (size_t)j * ED;
      float a = 0.0f;
      #pragma unroll
      for (int k = 0; k < ED; ++k) a = fmaf(Z[wv][k], e[k], a);  // sequential f32 chain
      const float d = (z2v + e2[j]) - 2.0f * a;
      if (d < bm) { bm = d; bi = j; }
    }
    #pragma unroll
    for (int off = 1; off < 64; off <<= 1) {
      const float om = __shfl_xor(bm, off, 64);
      const int   oi = __shfl_xor(bi, off, 64);
      if (om < bm || (om == bm && oi < bi)) { bm = om; bi = oi; }
    }
    if (lane == 0) idxf[n] = (float)bi;
    __builtin_amdgcn_wave_barrier();
  }
}

// ---- z_q gather + per-block loss partial ----
__global__ __launch_bounds__(256) void k_zq(const float* __restrict__ z,
    const float* __restrict__ cb, const float* __restrict__ idxf,
    float* __restrict__ zq, float* __restrict__ partial) {
  const int o = blockIdx.x * 256 + threadIdx.x;
  const int b = o >> 16;
  const int d = (o >> 10) & 63;
  const int hw = o & 1023;
  const int n = (b << 10) + hw;
  const int idx = (int)idxf[n];
  const float v = cb[(size_t)idx * ED + d];
  zq[o] = v;
  const float diff = z[o] - v;
  float s = diff * diff;
  #pragma unroll
  for (int off = 32; off > 0; off >>= 1) s += __shfl_xor(s, off, 64);
  __shared__ float sh[4];
  if ((threadIdx.x & 63) == 0) sh[threadIdx.x >> 6] = s;
  __syncthreads();
  if (threadIdx.x == 0)
    partial[blockIdx.x] = (sh[0] + sh[1]) + (sh[2] + sh[3]);
}

__global__ void k_loss(const float* __restrict__ partial, float* __restrict__ out0) {
  const int t = threadIdx.x;
  double s = 0.0;
  #pragma unroll
  for (int k = 0; k < NBLK_ZQ / 256; ++k) s += (double)partial[t + (k << 8)];
  #pragma unroll
  for (int off = 32; off > 0; off >>= 1) s += __shfl_xor(s, off, 64);
  __shared__ double sh[4];
  if ((t & 63) == 0) sh[t >> 6] = s;
  __syncthreads();
  if (t == 0)
    out0[0] = (float)(1.25 * ((sh[0] + sh[1]) + (sh[2] + sh[3])) / 4194304.0);
}

__global__ __launch_bounds__(256) void k_fill(float* __restrict__ me) {
  const size_t n4 = (ME_FLOATS - 3) >> 2;
  float4* __restrict__ p4 = reinterpret_cast<float4*>(me + 3);
  const size_t stride = (size_t)gridDim.x * blockDim.x;
  const float4 zero4 = make_float4(0.f, 0.f, 0.f, 0.f);
  for (size_t i = blockIdx.x * (size_t)blockDim.x + threadIdx.x; i < n4; i += stride)
    p4[i] = zero4;
  if (blockIdx.x == 0 && threadIdx.x == 0) {
    me[0] = 0.f; me[1] = 0.f; me[2] = 0.f;
    me[ME_FLOATS - 1] = 0.f;
  }
}

__global__ void k_scatter(const float* __restrict__ idxf, float* __restrict__ me) {
  const int n = blockIdx.x * 256 + threadIdx.x;
  const int idx = (int)idxf[n];
  me[(size_t)n * NE + idx] = 1.0f;
}

extern "C" void kernel_launch(void* const* d_in, const int* in_sizes, int n_in,
                              void* d_out, int out_size, void* d_ws, size_t ws_size,
                              hipStream_t stream) {
  const float* z  = (const float*)d_in[0];
  const float* cb = (const float*)d_in[1];
  float* out  = (float*)d_out;
  float* zq   = out + OFF_ZQ;
  float* me   = out + OFF_ME;
  float* idxf = out + OFF_IDX;
  float* base = me + 3;                      // 16B-aligned scratch in one-hot region
  short* zfrag   = (short*)(base + SC_ZFRAG);
  short* cbfrag  = (short*)(base + SC_CBFRAG);
  float* z2      = base + SC_Z2;
  float* partial = base + SC_PARTIAL;
  int*   flagged = (int*)(base + SC_FLAG);
  float* e2  = (float*)((char*)d_ws + 16);
  int*   cnt = (int*)((char*)d_ws + 8);

  k_e2<<<16, 64, 0, stream>>>(cb, e2, cnt);
  k_z2<<<N_ROWS / 256, 256, 0, stream>>>(z, z2);
  k_split_z<<<1024, 256, 0, stream>>>(z, zfrag);
  k_split_cb<<<16, 256, 0, stream>>>(cb, cbfrag);
  k_mfma2<<<N_ROWS / 128, 256, 0, stream>>>(zfrag, cbfrag, e2, z2, idxf, flagged, cnt);
  k_exact<<<256, 256, 0, stream>>>(z, cb, e2, z2, flagged, cnt, idxf);
  k_zq<<<NBLK_ZQ, 256, 0, stream>>>(z, cb, idxf, zq, partial);
  k_loss<<<1, 256, 0, stream>>>(partial, out);
  k_fill<<<2048, 256, 0, stream>>>(me);
  k_scatter<<<N_ROWS / 256, 256, 0, stream>>>(idxf, me);
}